// Round 6
// baseline (42.029 us; speedup 1.0000x reference)
//
#include <hip/hip_runtime.h>
#include <hip/hip_fp16.h>
#include <math.h>

// Problem constants (match reference)
#define BB 64
#define HH 224
#define WW 224
#define CC 3

constexpr float FACTOR  = 0.2f;
constexpr float SCALE_K = 1.0f / 255.0f;
constexpr float TWO_PI_F = 6.283185307179586f;
constexpr float CX = (WW - 1) * 0.5f;            // 111.5
constexpr float CY = (HH - 1) * 0.5f;            // 111.5
constexpr int PIX = HH * WW;                     // 50176
constexpr int IMG_ELEMS = PIX * CC;              // 150528

constexpr int TILES_X = WW / 16;                 // 14
constexpr int TILES_PER_IMG = TILES_X * TILES_X; // 196
constexpr int NXCD = 8;
constexpr int NBLOCKS = BB * TILES_PER_IMG;      // 12544

typedef float f32x4 __attribute__((ext_vector_type(4), aligned(4)));
typedef unsigned int u32x4 __attribute__((ext_vector_type(4), aligned(8)));

// Valid for i in [-n, 2n-1] — true for every coordinate in this pipeline.
__device__ __forceinline__ int reflect1(int i, int n) {
    i = (i < 0) ? (-1 - i) : i;
    return (i >= n) ? (2 * n - 1 - i) : i;
}

// Hull [lo,hi] of reflect1 over the integer range [a,b] (piecewise-V: extremes
// are the endpoints plus the fold apexes at {-1,0} (->0) and {n-1,n} (->n-1)).
__device__ __forceinline__ void rhull(int a, int b, int n, int& lo, int& hi) {
    int ra = reflect1(a, n), rb = reflect1(b, n);
    lo = min(ra, rb); hi = max(ra, rb);
    if (a <= 0 && b >= -1) lo = 0;
    if (b >= n - 1 && a <= n) hi = n - 1;
}

// block i -> XCD i%8 (HW round-robin); batch b pinned to XCD b%8 in BOTH
// kernels so zoomshift's tmp reads hit the L2 rotate wrote.
__device__ __forceinline__ void decode_tile(int bid, int& b, int& tx, int& ty) {
    int xcd  = bid & (NXCD - 1);
    int slot = bid >> 3;
    int bi   = slot / TILES_PER_IMG;
    int t    = slot - bi * TILES_PER_IMG;
    b = xcd + bi * NXCD;
    ty = t / TILES_X;
    tx = t - ty * TILES_X;
}

__device__ __forceinline__ void up3(uint2 v, float* o) {
    o[0] = __half2float(__ushort_as_half((unsigned short)(v.x & 0xffffu)));
    o[1] = __half2float(__ushort_as_half((unsigned short)(v.x >> 16)));
    o[2] = __half2float(__ushort_as_half((unsigned short)(v.y & 0xffffu)));
}

__device__ __forceinline__ uint2 pack3(float a, float b, float c) {
    uint2 v;
    v.x = (unsigned)__half_as_ushort(__float2half_rn(a)) |
          ((unsigned)__half_as_ushort(__float2half_rn(b)) << 16);
    v.y = (unsigned)__half_as_ushort(__float2half_rn(c));
    return v;
}

// pass 1: rescale + rotate, all taps from an LDS-staged bbox.
// Rotated bbox of a 16x16 tile: span 15*(|c|+|s|)+1 taps <= 24 values each
// axis. Stage the reflect-clamped hull (contiguous in-image rows) with
// coalesced loads; taps reflect into the hull. Clamped tap indices can only
// be hit with ~0 bilinear weight (ulp cases), so clamping is safe.
__global__ __launch_bounds__(256)
void rotate_kernel(const float* __restrict__ image, uint2* __restrict__ tmp,
                   const float* __restrict__ angle_u) {
    __shared__ float4 S[24][33];   // pitch 33*16B: bank shift 4/row
    int b, tx, ty;
    decode_tile(blockIdx.x, b, tx, ty);
    const int ox = tx * 16, oy = ty * 16;

    const float theta = (2.0f * angle_u[b] - 1.0f) * FACTOR * TWO_PI_F;
    const float c = __cosf(theta), s = __sinf(theta);

    // exact corner extremes of the affine map over the tile
    const float rx0 = (float)ox - CX, rx1 = (float)(ox + 15) - CX;
    const float ry0 = (float)oy - CY, ry1 = (float)(oy + 15) - CY;
    const int Xlo = (int)floorf(fminf(c * rx0, c * rx1) + fminf(-s * ry0, -s * ry1) + CX);
    const int Xhi = (int)floorf(fmaxf(c * rx0, c * rx1) + fmaxf(-s * ry0, -s * ry1) + CX) + 1;
    const int Ylo = (int)floorf(fminf(s * rx0, s * rx1) + fminf(c * ry0, c * ry1) + CY);
    const int Yhi = (int)floorf(fmaxf(s * rx0, s * rx1) + fmaxf(c * ry0, c * ry1) + CY) + 1;
    int Cx0, Cx1, Cy0, Cy1;
    rhull(Xlo, Xhi, WW, Cx0, Cx1);
    rhull(Ylo, Yhi, HH, Cy0, Cy1);

    const float* img = image + (size_t)b * IMG_ELEMS;
    {
        const int lc  = threadIdx.x & 31;
        const int col = min(Cx0 + lc, WW - 1);
#pragma unroll
        for (int it = 0; it < 3; ++it) {
            const int r   = it * 8 + (threadIdx.x >> 5);
            const int row = min(Cy0 + r, HH - 1);
            int pe = (row * WW + col) * CC;            // 12B/px, load 16B
            const bool last = pe > IMG_ELEMS - 4;      // only px (223,223)
            pe = min(pe, IMG_ELEMS - 4);
            f32x4 v = *(const f32x4*)(img + pe);
            S[r][lc] = last ? make_float4(v.y, v.z, v.w, 0.0f)
                            : make_float4(v.x, v.y, v.z, v.w);
        }
    }
    __syncthreads();

    const int x = ox + (threadIdx.x & 15), y = oy + (threadIdx.x >> 4);
    const float xs = c * ((float)x - CX) - s * ((float)y - CY) + CX;
    const float ys = s * ((float)x - CX) + c * ((float)y - CY) + CY;
    const float xf = floorf(xs), yf = floorf(ys);
    const float fx = xs - xf, fy = ys - yf;
    const int x0 = (int)xf, y0 = (int)yf;
    const int c0 = min(max(reflect1(x0,     WW) - Cx0, 0), 31);
    const int c1 = min(max(reflect1(x0 + 1, WW) - Cx0, 0), 31);
    const int r0 = min(max(reflect1(y0,     HH) - Cy0, 0), 23);
    const int r1 = min(max(reflect1(y0 + 1, HH) - Cy0, 0), 23);

    const float4 A  = S[r0][c0];
    const float4 Bv = S[r0][c1];
    const float4 Cv = S[r1][c0];
    const float4 Dv = S[r1][c1];

    const float ofx = 1.0f - fx, ofy = 1.0f - fy;
    const float o0 = ((A.x * ofx + Bv.x * fx) * ofy + (Cv.x * ofx + Dv.x * fx) * fy) * SCALE_K;
    const float o1 = ((A.y * ofx + Bv.y * fx) * ofy + (Cv.y * ofx + Dv.y * fx) * fy) * SCALE_K;
    const float o2 = ((A.z * ofx + Bv.z * fx) * ofy + (Cv.z * ofx + Dv.z * fx) * fy) * SCALE_K;

    tmp[(size_t)b * PIX + y * WW + x] = pack3(o0, o1, o2);
}

// pass 2+3 fused, all taps from LDS.
// Translate window (17x17 raw coords, batch-uniform fractional weights) ->
// reflect hull -> zoom tap grid G (<=22 values/axis, exact by monotonicity)
// -> reflect hull = contiguous in-image window (<=22x22) staged coalesced.
// Z[17][17] = zoom-stage values (exact reference FP tree, fp16-rounded like
// the R5 kernel); final blend uses uniform translate weights.
__global__ __launch_bounds__(256)
void zoomshift_kernel(const uint2* __restrict__ tmp, float* __restrict__ out,
                      const float* __restrict__ zoom_u,
                      const float* __restrict__ shift_u,
                      const float* __restrict__ flip_u) {
    __shared__ uint2 Sz[32][34];   // pitch 34*8B = 272B (16B-aligned rows)
    __shared__ uint2 Zl[17][18];
    int b, tx, ty;
    decode_tile(blockIdx.x, b, tx, ty);
    const int ox = tx * 16, oy = ty * 16;

    const float zh = 1.0f + (2.0f * zoom_u[2 * b + 0] - 1.0f) * FACTOR;
    const float zw = 1.0f + (2.0f * zoom_u[2 * b + 1] - 1.0f) * FACTOR;
    const float dy = ((2.0f * shift_u[2 * b + 0] - 1.0f) * FACTOR) * (float)HH;
    const float dx = ((2.0f * shift_u[2 * b + 1] - 1.0f) * FACTOR) * (float)WW;
    const bool flip = flip_u[b] > 0.5f;

    const float ndxf = floorf(-dx), ndyf = floorf(-dy);
    const int Kx = (int)ndxf, Ky = (int)ndyf;
    const float fx3 = -dx - ndxf, fy3 = -dy - ndyf;   // batch-uniform weights

    const int Xmin = (flip ? WW - 16 - ox : ox) + Kx;
    const int Ymin = oy + Ky;

    int XrLo, XrHi, YrLo, YrHi;
    rhull(Xmin, Xmin + 16, WW, XrLo, XrHi);
    rhull(Ymin, Ymin + 16, HH, YrLo, YrHi);

    // zoom tap grid (monotone in Xr -> exact bounds)
    const int Gx0 = (int)floorf(zw * ((float)XrLo - CX) + CX);
    const int Gx1 = (int)floorf(zw * ((float)XrHi - CX) + CX) + 1;
    const int Gy0 = (int)floorf(zh * ((float)YrLo - CY) + CY);
    const int Gy1 = (int)floorf(zh * ((float)YrHi - CY) + CY) + 1;
    int Cx0, Cx1, Cy0, Cy1;
    rhull(Gx0, Gx1, WW, Cx0, Cx1);
    rhull(Gy0, Gy1, HH, Cy0, Cy1);
    const int CxA = Cx0 & ~1;      // align pair loads to 16B

    const uint2* timg = tmp + (size_t)b * PIX;
    {
        const int cp  = (threadIdx.x & 15) * 2;
        const int col = min(CxA + cp, WW - 2);
#pragma unroll
        for (int it = 0; it < 2; ++it) {
            const int r   = it * 16 + (threadIdx.x >> 4);
            const int row = min(Cy0 + r, HH - 1);
            u32x4 v = *(const u32x4*)(timg + row * WW + col);
            *(u32x4*)(&Sz[r][cp]) = v;
        }
    }
    __syncthreads();

    for (int e = threadIdx.x; e < 17 * 17; e += 256) {
        const int ey = e / 17, ex = e - ey * 17;
        const int Xr = reflect1(Xmin + ex, WW);
        const int Yr = reflect1(Ymin + ey, HH);
        const float xs2 = zw * ((float)Xr - CX) + CX;   // exact reference expr
        const float ys2 = zh * ((float)Yr - CY) + CY;
        const float xf = floorf(xs2), yf = floorf(ys2);
        const float fx2 = xs2 - xf, fy2 = ys2 - yf;
        const int x20 = (int)xf, y20 = (int)yf;
        const int cA = min(max(reflect1(x20,     WW) - CxA, 0), 31);
        const int cB = min(max(reflect1(x20 + 1, WW) - CxA, 0), 31);
        const int rA = min(max(reflect1(y20,     HH) - Cy0, 0), 31);
        const int rB = min(max(reflect1(y20 + 1, HH) - Cy0, 0), 31);

        float A[3], Bv[3], Cv[3], Dv[3];
        up3(Sz[rA][cA], A);  up3(Sz[rA][cB], Bv);
        up3(Sz[rB][cA], Cv); up3(Sz[rB][cB], Dv);

        const float ofx = 1.0f - fx2, ofy = 1.0f - fy2;
        const float z0 = (A[0] * ofx + Bv[0] * fx2) * ofy + (Cv[0] * ofx + Dv[0] * fx2) * fy2;
        const float z1 = (A[1] * ofx + Bv[1] * fx2) * ofy + (Cv[1] * ofx + Dv[1] * fx2) * fy2;
        const float z2 = (A[2] * ofx + Bv[2] * fx2) * ofy + (Cv[2] * ofx + Dv[2] * fx2) * fy2;
        Zl[ey][ex] = pack3(z0, z1, z2);
    }
    __syncthreads();

    const int lx = threadIdx.x & 15, ly = threadIdx.x >> 4;
    const int ix = flip ? (15 - lx) : lx;   // flip folded into window lookup
    float A[3], Bv[3], Cv[3], Dv[3];
    up3(Zl[ly][ix],     A);  up3(Zl[ly][ix + 1],     Bv);
    up3(Zl[ly + 1][ix], Cv); up3(Zl[ly + 1][ix + 1], Dv);

    float* o = out + ((size_t)b * PIX + (size_t)(oy + ly) * WW + (ox + lx)) * CC;
    const float ofx = 1.0f - fx3, ofy = 1.0f - fy3;
    o[0] = (A[0] * ofx + Bv[0] * fx3) * ofy + (Cv[0] * ofx + Dv[0] * fx3) * fy3;
    o[1] = (A[1] * ofx + Bv[1] * fx3) * ofy + (Cv[1] * ofx + Dv[1] * fx3) * fy3;
    o[2] = (A[2] * ofx + Bv[2] * fx3) * ofy + (Cv[2] * ofx + Dv[2] * fx3) * fy3;
}

extern "C" void kernel_launch(void* const* d_in, const int* in_sizes, int n_in,
                              void* d_out, int out_size, void* d_ws, size_t ws_size,
                              hipStream_t stream) {
    const float* image   = (const float*)d_in[0];
    const float* angle_u = (const float*)d_in[1];
    const float* zoom_u  = (const float*)d_in[2];
    const float* shift_u = (const float*)d_in[3];
    const float* flip_u  = (const float*)d_in[4];
    float* out = (float*)d_out;

    uint2* tmp = (uint2*)d_ws;   // B*H*W packed fp16 RGBA, 25.7 MB

    // pass 1: rescale + rotate   image -> tmp (fp16)
    rotate_kernel<<<NBLOCKS, 256, 0, stream>>>(image, tmp, angle_u);
    // pass 2+3 fused: zoom + translate + flip   tmp -> d_out
    zoomshift_kernel<<<NBLOCKS, 256, 0, stream>>>(tmp, out, zoom_u, shift_u, flip_u);
}